// Round 8
// baseline (105.395 us; speedup 1.0000x reference)
//
#include <hip/hip_runtime.h>

#define B 256
#define N 512
#define M 512
#define BM (B * M)   // 131072
#define NM (N * M)   // 262144

// ===========================================================================
// k_a: one launch, 642 blocks x 256 threads.
//  blk 0..511  : relxA tiles  px[z][m][n] = sum_{b in chunk z} min(x,t)
//  blk 512..543: xT tiles   blk 544..607: wT tiles   blk 608..639: tT tiles
//  blk 640/641 : sum_x / sum_w (f64, bit-identical order to R1..R7)
// ===========================================================================
__device__ __forceinline__ void tile_tr256(const float* __restrict__ src,
                                           float* __restrict__ dst,
                                           int R, int C, int r0, int c0, int tid) {
    __shared__ float s[64][65];
    const int tx = tid & 63, q = tid >> 6;
    #pragma unroll
    for (int j = 0; j < 16; ++j) {
        int rl = q * 16 + j;
        s[rl][tx] = src[(r0 + rl) * C + c0 + tx];
    }
    __syncthreads();
    #pragma unroll
    for (int j = 0; j < 16; ++j) {
        int cl = q * 16 + j;
        dst[(c0 + cl) * R + r0 + tx] = s[tx][cl];
    }
}

__global__ __launch_bounds__(256) void k_a(const float* __restrict__ x,
                                           const float* __restrict__ w,
                                           const float* __restrict__ t,
                                           float* __restrict__ xT,
                                           float* __restrict__ wT,
                                           float* __restrict__ tT,
                                           float* __restrict__ sum_x,
                                           float* __restrict__ sum_w,
                                           float* __restrict__ px) {
    const int blk = blockIdx.x, tid = threadIdx.x;
    if (blk < 512) {
        // ---- relxA: tile 64m x 32n, thread = 4m x 2n, z-chunk of 64 b ----
        const int z   = blk >> 7;
        const int rem = blk & 127;
        const int m0 = (rem & 7) * 64;
        const int n0 = (rem >> 3) * 32;
        const int tx = tid & 15, ty = tid >> 4;      // tx: m-group, ty: n-group
        __shared__ float s_t[32][64];                // [b-local][m-local]
        __shared__ float s_x[32][36];                // [b-local][n-local]+pad
        const int sr = tid >> 3, sc = tid & 7;
        float aA0 = 0.f, aA1 = 0.f, aA2 = 0.f, aA3 = 0.f;
        float aB0 = 0.f, aB1 = 0.f, aB2 = 0.f, aB3 = 0.f;
        const int nA = ty * 2, nB = nA + 1;
        for (int scnk = 0; scnk < 2; ++scnk) {
            const int bb = z * 64 + scnk * 32;
            __syncthreads();
            *(float4*)&s_t[sr][sc * 8]     = *(const float4*)&t[(bb + sr) * M + m0 + sc * 8];
            *(float4*)&s_t[sr][sc * 8 + 4] = *(const float4*)&t[(bb + sr) * M + m0 + sc * 8 + 4];
            *(float4*)&s_x[sr][sc * 4]     = *(const float4*)&x[(bb + sr) * N + n0 + sc * 4];
            __syncthreads();
            #pragma unroll 8
            for (int i = 0; i < 32; ++i) {           // b ascending: bit-identical
                float4 tv = *(const float4*)&s_t[i][tx * 4];
                float xA = s_x[i][nA], xB = s_x[i][nB];
                aA0 += fminf(xA, tv.x); aA1 += fminf(xA, tv.y);
                aA2 += fminf(xA, tv.z); aA3 += fminf(xA, tv.w);
                aB0 += fminf(xB, tv.x); aB1 += fminf(xB, tv.y);
                aB2 += fminf(xB, tv.z); aB3 += fminf(xB, tv.w);
            }
        }
        // stage 64x32 output tile in LDS (reuse s_t), store coalesced
        __syncthreads();
        float* so = &s_t[0][0];                      // [m-local*32 + n-local]
        so[(tx * 4 + 0) * 32 + nA] = aA0; so[(tx * 4 + 0) * 32 + nB] = aB0;
        so[(tx * 4 + 1) * 32 + nA] = aA1; so[(tx * 4 + 1) * 32 + nB] = aB1;
        so[(tx * 4 + 2) * 32 + nA] = aA2; so[(tx * 4 + 2) * 32 + nB] = aB2;
        so[(tx * 4 + 3) * 32 + nA] = aA3; so[(tx * 4 + 3) * 32 + nB] = aB3;
        __syncthreads();
        const int m_l = tid >> 2, n_l = (tid & 3) * 8;
        float* dst = &px[z * NM + (m0 + m_l) * N + n0 + n_l];
        *(float4*)&dst[0] = *(const float4*)&so[m_l * 32 + n_l];
        *(float4*)&dst[4] = *(const float4*)&so[m_l * 32 + n_l + 4];
    } else if (blk < 544) {
        int id = blk - 512;
        tile_tr256(x, xT, B, N, (id >> 3) * 64, (id & 7) * 64, tid);
    } else if (blk < 608) {
        int id = blk - 544;
        tile_tr256(w, wT, N, M, (id >> 3) * 64, (id & 7) * 64, tid);
    } else if (blk < 640) {
        int id = blk - 608;
        tile_tr256(t, tT, B, M, (id >> 3) * 64, (id & 7) * 64, tid);
    } else if (blk == 640) {
        for (int i = tid; i < N; i += 256) {
            double a0 = 0, a1 = 0, a2 = 0, a3 = 0;
            for (int b = 0; b < B; b += 4) {
                a0 += (double)x[(b + 0) * N + i];
                a1 += (double)x[(b + 1) * N + i];
                a2 += (double)x[(b + 2) * N + i];
                a3 += (double)x[(b + 3) * N + i];
            }
            sum_x[i] = (float)((a0 + a1) + (a2 + a3));
        }
    } else {
        for (int mm = tid; mm < M; mm += 256) {
            double a0 = 0, a1 = 0, a2 = 0, a3 = 0;
            for (int n = 0; n < N; n += 4) {
                a0 += (double)w[(n + 0) * M + mm];
                a1 += (double)w[(n + 1) * M + mm];
                a2 += (double)w[(n + 2) * M + mm];
                a3 += (double)w[(n + 3) * M + mm];
            }
            sum_w[mm] = (float)((a0 + a1) + (a2 + a3));
        }
    }
}

// ===========================================================================
// k_col: one block per column m; R7 logic with wave-level scans (7 barriers).
// ===========================================================================
__global__ __launch_bounds__(512) void k_col(
        const float* __restrict__ x, const float* __restrict__ xT,
        const float* __restrict__ wT, const float* __restrict__ tT,
        const float* __restrict__ px, const float* __restrict__ sum_x,
        const float* __restrict__ sum_w, float* __restrict__ out) {
    const int m = blockIdx.x, tid = threadIdx.x;
    const int lane = tid & 63, wid = tid >> 6;

    __shared__ float  worig[512], pm[512], wsrt[512];
    __shared__ float  srx_r[512], srx_u[512];
    __shared__ int    srx_n[512];
    __shared__ int    cnt[256], cbase[256], cslot[256];
    __shared__ int    rcnt[256], rbase[256], rslot[256], rbmax[256];
    __shared__ double bsumI[256];
    __shared__ float  wtotmax[8], red3[3][8];
    __shared__ int    ctot[4], rtot[4];
    __shared__ double btot[4];

    // ---- loads (bit-identical rv expression to R7) ----
    const float wv = wT[m * N + tid];
    float p = px[m * N + tid];
    p += px[NM + m * N + tid];
    p += px[2 * NM + m * N + tid];
    p += px[3 * NM + m * N + tid];
    const float rv = p / sum_x[tid];
    worig[tid] = wv;
    if (tid < 256) { cnt[tid] = 0; rcnt[tid] = 0; cslot[tid] = 0; rslot[tid] = 0; rbmax[tid] = 0; }

    // ---- wave prefix-max (pm) + wave reductions (wmin,rmin,rmax) ----
    float pmv = wv;
    #pragma unroll
    for (int off = 1; off < 64; off <<= 1) {
        float o = __shfl_up(pmv, off, 64);
        if (lane >= off) pmv = fmaxf(pmv, o);
    }
    if (lane == 63) wtotmax[wid] = pmv;
    float wmn = wv, rmn = rv, rmx = rv;
    #pragma unroll
    for (int off = 32; off > 0; off >>= 1) {
        wmn = fminf(wmn, __shfl_xor(wmn, off, 64));
        rmn = fminf(rmn, __shfl_xor(rmn, off, 64));
        rmx = fmaxf(rmx, __shfl_xor(rmx, off, 64));
    }
    if (lane == 0) { red3[0][wid] = wmn; red3[1][wid] = rmn; red3[2][wid] = rmx; }
    __syncthreads();                                           // (1)

    {
        float om = -1e30f;
        for (int j = 0; j < wid; ++j) om = fmaxf(om, wtotmax[j]);
        pm[tid] = fmaxf(pmv, om);
    }
    float wmin = red3[0][0], rmin = red3[1][0], rmax = red3[2][0], wmax = wtotmax[0];
    #pragma unroll
    for (int j = 1; j < 8; ++j) {
        wmin = fminf(wmin, red3[0][j]);
        rmin = fminf(rmin, red3[1][j]);
        rmax = fmaxf(rmax, red3[2][j]);
        wmax = fmaxf(wmax, wtotmax[j]);
    }

    // ---- histograms (same bucketing as R7) ----
    const float wscale = 255.0f / fmaxf(wmax - wmin, 1e-30f);
    int wk = (int)((wv - wmin) * wscale);
    wk = wk < 0 ? 0 : (wk > 255 ? 255 : wk);
    atomicAdd(&cnt[wk], 1);
    const float rscale = 255.0f / fmaxf(rmax - rmin, 1e-30f);
    int rk;
    { int kv = (int)((rv - rmin) * rscale); kv = kv < 0 ? 0 : (kv > 255 ? 255 : kv); rk = 255 - kv; }
    atomicAdd(&rcnt[rk], 1);
    atomicMax(&rbmax[rk], __float_as_int(rv));                 // rv > 0
    __syncthreads();                                           // (2)

    // ---- both 256-prefix-sums concurrently: waves 0-3 cnt, waves 4-7 rcnt ----
    int myc = (tid < 256) ? cnt[tid] : rcnt[tid - 256];
    int incl = myc;
    #pragma unroll
    for (int off = 1; off < 64; off <<= 1) {
        int o = __shfl_up(incl, off, 64);
        if (lane >= off) incl += o;
    }
    if (lane == 63) { if (wid < 4) ctot[wid] = incl; else rtot[wid - 4] = incl; }
    __syncthreads();                                           // (3)
    if (tid < 256) {
        int eo = 0;
        for (int j = 0; j < wid; ++j) eo += ctot[j];
        cbase[tid] = eo + incl - myc;
    } else {
        int eo = 0, w2 = wid - 4;
        for (int j = 0; j < w2; ++j) eo += rtot[j];
        rbase[tid - 256] = eo + incl - myc;
    }
    __syncthreads();                                           // (4)

    // ---- scatter (bucket-ordered) ----
    { int p1 = cbase[wk] + atomicAdd(&cslot[wk], 1); wsrt[p1] = wv; }
    { int p2 = rbase[rk] + atomicAdd(&rslot[rk], 1);
      srx_r[p2] = rv; srx_n[p2] = tid; srx_u[p2] = __int_as_float(rbmax[rk]); }
    __syncthreads();                                           // (5)

    // ---- per-bucket f64 sums + 256-prefix (waves 0-3) ----
    double bincl = 0.0, mysum = 0.0;
    if (tid < 256) {
        int st = cbase[tid], e = st + cnt[tid];
        for (int i = st; i < e; ++i) mysum += (double)wsrt[i];
        bincl = mysum;
        #pragma unroll
        for (int off = 1; off < 64; off <<= 1) {
            double o = __shfl_up(bincl, off, 64);
            if (lane >= off) bincl += o;
        }
        if (lane == 63) btot[wid] = bincl;
    }
    __syncthreads();                                           // (6)
    if (tid < 256) {
        double eo = 0.0;
        for (int j = 0; j < wid; ++j) eo += btot[j];
        bsumI[tid] = eo + bincl;
    }
    __syncthreads();                                           // (7)

    if (tid < 256) {
        // ==== phase C: ind_w scan, descending-rel buckets (waves 0-3) ====
        const int b = tid;
        float bv = -1.0f; int bi = 0;
        for (int i = 0; i < 512; ++i) {
            float u = srx_u[i];                      // non-increasing bound
            if (__ballot(u >= bv) == 0ULL) break;
            float r = srx_r[i];
            int   n = srx_n[i];
            float xv = xT[n * B + b];                // coalesced
            float v = fminf(xv, r);
            if (v > bv || (v == bv && n < bi)) { bv = v; bi = n; }
        }
        out[BM + b * M + m] = fminf(x[b * N + bi], worig[bi]);   // chosen_w
    } else {
        // ==== phase D: rel_w CDF + ind_x (waves 4-7) ====
        const int b = tid - 256;
        const float tbm = tT[m * B + b];
        float btf = (tbm - wmin) * wscale;
        int kk; double S;
        if (btf < 0.0f) { kk = 0; S = 0.0; }
        else {
            int bt = (int)btf; bt = bt > 255 ? 255 : bt;
            kk = cbase[bt];
            S = (bt > 0) ? bsumI[bt - 1] : 0.0;
            int e = cbase[bt] + cnt[bt];
            for (int i = cbase[bt]; i < e; ++i) {
                float v = wsrt[i];
                if (v < tbm) { ++kk; S += (double)v; }
            }
        }
        double rw = S + (double)tbm * (double)(512 - kk);
        float c = (float)rw / sum_w[m];
        float tgt = fminf(c, pm[511]);
        int lo = 0, hi = 511;
        while (lo < hi) { int mid = (lo + hi) >> 1; if (pm[mid] >= tgt) hi = mid; else lo = mid + 1; }
        const int ind = lo;
        out[b * M + m] = fminf(x[b * N + ind], worig[ind]);      // chosen_x
    }
}

extern "C" void kernel_launch(void* const* d_in, const int* in_sizes, int n_in,
                              void* d_out, int out_size, void* d_ws, size_t ws_size,
                              hipStream_t stream) {
    const float* x = (const float*)d_in[0];  // (B, N)
    const float* w = (const float*)d_in[1];  // (N, M)
    const float* t = (const float*)d_in[2];  // (B, M)
    float* out = (float*)d_out;

    float* ws = (float*)d_ws;
    float* xT    = ws;                 // 131072
    float* wT    = ws + 131072;        // 262144
    float* tT    = ws + 393216;        // 131072
    float* sum_x = ws + 524288;        // 512
    float* sum_w = ws + 524800;        // 512
    float* px    = ws + 525312;        // 4*NM = 1048576  (~6.3 MB total)

    k_a  <<<642, 256, 0, stream>>>(x, w, t, xT, wT, tT, sum_x, sum_w, px);
    k_col<<<512, 512, 0, stream>>>(x, xT, wT, tT, px, sum_x, sum_w, out);
}

// Round 9
// 89.291 us; speedup vs baseline: 1.1804x; 1.1804x over previous
//
#include <hip/hip_runtime.h>

#define B 256
#define N 512
#define M 512
#define BM (B * M)   // 131072
#define NM (N * M)   // 262144

// ===========================================================================
// k_a: one launch, 644 blocks x 256 threads. Short blocks FIRST so the
// homogeneous relx blocks (not the serial sum tails) are the stragglers.
//  blk 0..31   : xT tiles    blk 32..95: wT tiles    blk 96..127: tT tiles
//  blk 128..129: sum_x (1 elem/thread, bit-identical per-element f64 order)
//  blk 130..131: sum_w (likewise)
//  blk 132..643: relxA tiles  px[z][m][n] = sum_{b in chunk z} min(x,t)
// ===========================================================================
__device__ __forceinline__ void tile_tr256(const float* __restrict__ src,
                                           float* __restrict__ dst,
                                           int R, int C, int r0, int c0, int tid) {
    __shared__ float s[64][65];
    const int tx = tid & 63, q = tid >> 6;
    #pragma unroll
    for (int j = 0; j < 16; ++j) {
        int rl = q * 16 + j;
        s[rl][tx] = src[(r0 + rl) * C + c0 + tx];
    }
    __syncthreads();
    #pragma unroll
    for (int j = 0; j < 16; ++j) {
        int cl = q * 16 + j;
        dst[(c0 + cl) * R + r0 + tx] = s[tx][cl];
    }
}

__global__ __launch_bounds__(256) void k_a(const float* __restrict__ x,
                                           const float* __restrict__ w,
                                           const float* __restrict__ t,
                                           float* __restrict__ xT,
                                           float* __restrict__ wT,
                                           float* __restrict__ tT,
                                           float* __restrict__ sum_x,
                                           float* __restrict__ sum_w,
                                           float* __restrict__ px) {
    const int blk = blockIdx.x, tid = threadIdx.x;
    if (blk < 32) {
        tile_tr256(x, xT, B, N, (blk >> 3) * 64, (blk & 7) * 64, tid);
    } else if (blk < 96) {
        int id = blk - 32;
        tile_tr256(w, wT, N, M, (id >> 3) * 64, (id & 7) * 64, tid);
    } else if (blk < 128) {
        int id = blk - 96;
        tile_tr256(t, tT, B, M, (id >> 3) * 64, (id & 7) * 64, tid);
    } else if (blk < 130) {
        const int i = (blk - 128) * 256 + tid;       // one element per thread
        double a0 = 0, a1 = 0, a2 = 0, a3 = 0;
        for (int b = 0; b < B; b += 4) {
            a0 += (double)x[(b + 0) * N + i];
            a1 += (double)x[(b + 1) * N + i];
            a2 += (double)x[(b + 2) * N + i];
            a3 += (double)x[(b + 3) * N + i];
        }
        sum_x[i] = (float)((a0 + a1) + (a2 + a3));
    } else if (blk < 132) {
        const int mm = (blk - 130) * 256 + tid;
        double a0 = 0, a1 = 0, a2 = 0, a3 = 0;
        for (int n = 0; n < N; n += 4) {
            a0 += (double)w[(n + 0) * M + mm];
            a1 += (double)w[(n + 1) * M + mm];
            a2 += (double)w[(n + 2) * M + mm];
            a3 += (double)w[(n + 3) * M + mm];
        }
        sum_w[mm] = (float)((a0 + a1) + (a2 + a3));
    } else {
        // ---- relxA: tile 64m x 32n, thread = 4m x 2n, z-chunk of 64 b ----
        const int rb  = blk - 132;
        const int z   = rb >> 7;
        const int rem = rb & 127;
        const int m0 = (rem & 7) * 64;
        const int n0 = (rem >> 3) * 32;
        const int tx = tid & 15, ty = tid >> 4;      // tx: m-group, ty: n-group
        __shared__ float s_t[32][64];                // [b-local][m-local]
        __shared__ float s_x[32][36];                // [b-local][n-local]+pad
        const int sr = tid >> 3, sc = tid & 7;
        float aA0 = 0.f, aA1 = 0.f, aA2 = 0.f, aA3 = 0.f;
        float aB0 = 0.f, aB1 = 0.f, aB2 = 0.f, aB3 = 0.f;
        const int nA = ty * 2, nB = nA + 1;
        for (int scnk = 0; scnk < 2; ++scnk) {
            const int bb = z * 64 + scnk * 32;
            __syncthreads();
            *(float4*)&s_t[sr][sc * 8]     = *(const float4*)&t[(bb + sr) * M + m0 + sc * 8];
            *(float4*)&s_t[sr][sc * 8 + 4] = *(const float4*)&t[(bb + sr) * M + m0 + sc * 8 + 4];
            *(float4*)&s_x[sr][sc * 4]     = *(const float4*)&x[(bb + sr) * N + n0 + sc * 4];
            __syncthreads();
            #pragma unroll 8
            for (int i = 0; i < 32; ++i) {           // b ascending: bit-identical
                float4 tv = *(const float4*)&s_t[i][tx * 4];
                float xA = s_x[i][nA], xB = s_x[i][nB];
                aA0 += fminf(xA, tv.x); aA1 += fminf(xA, tv.y);
                aA2 += fminf(xA, tv.z); aA3 += fminf(xA, tv.w);
                aB0 += fminf(xB, tv.x); aB1 += fminf(xB, tv.y);
                aB2 += fminf(xB, tv.z); aB3 += fminf(xB, tv.w);
            }
        }
        // stage 64x32 output tile in LDS (reuse s_t), store coalesced
        __syncthreads();
        float* so = &s_t[0][0];                      // [m-local*32 + n-local]
        so[(tx * 4 + 0) * 32 + nA] = aA0; so[(tx * 4 + 0) * 32 + nB] = aB0;
        so[(tx * 4 + 1) * 32 + nA] = aA1; so[(tx * 4 + 1) * 32 + nB] = aB1;
        so[(tx * 4 + 2) * 32 + nA] = aA2; so[(tx * 4 + 2) * 32 + nB] = aB2;
        so[(tx * 4 + 3) * 32 + nA] = aA3; so[(tx * 4 + 3) * 32 + nB] = aB3;
        __syncthreads();
        const int m_l = tid >> 2, n_l = (tid & 3) * 8;
        float* dst = &px[z * NM + (m0 + m_l) * N + n0 + n_l];
        *(float4*)&dst[0] = *(const float4*)&so[m_l * 32 + n_l];
        *(float4*)&dst[4] = *(const float4*)&so[m_l * 32 + n_l + 4];
    }
}

// ===========================================================================
// k_col: one block per column m (identical to R8, absmax 0 proven).
// ===========================================================================
__global__ __launch_bounds__(512) void k_col(
        const float* __restrict__ x, const float* __restrict__ xT,
        const float* __restrict__ wT, const float* __restrict__ tT,
        const float* __restrict__ px, const float* __restrict__ sum_x,
        const float* __restrict__ sum_w, float* __restrict__ out) {
    const int m = blockIdx.x, tid = threadIdx.x;
    const int lane = tid & 63, wid = tid >> 6;

    __shared__ float  worig[512], pm[512], wsrt[512];
    __shared__ float  srx_r[512], srx_u[512];
    __shared__ int    srx_n[512];
    __shared__ int    cnt[256], cbase[256], cslot[256];
    __shared__ int    rcnt[256], rbase[256], rslot[256], rbmax[256];
    __shared__ double bsumI[256];
    __shared__ float  wtotmax[8], red3[3][8];
    __shared__ int    ctot[4], rtot[4];
    __shared__ double btot[4];

    // ---- loads (bit-identical rv expression to R7/R8) ----
    const float wv = wT[m * N + tid];
    float p = px[m * N + tid];
    p += px[NM + m * N + tid];
    p += px[2 * NM + m * N + tid];
    p += px[3 * NM + m * N + tid];
    const float rv = p / sum_x[tid];
    worig[tid] = wv;
    if (tid < 256) { cnt[tid] = 0; rcnt[tid] = 0; cslot[tid] = 0; rslot[tid] = 0; rbmax[tid] = 0; }

    // ---- wave prefix-max (pm) + wave reductions (wmin,rmin,rmax) ----
    float pmv = wv;
    #pragma unroll
    for (int off = 1; off < 64; off <<= 1) {
        float o = __shfl_up(pmv, off, 64);
        if (lane >= off) pmv = fmaxf(pmv, o);
    }
    if (lane == 63) wtotmax[wid] = pmv;
    float wmn = wv, rmn = rv, rmx = rv;
    #pragma unroll
    for (int off = 32; off > 0; off >>= 1) {
        wmn = fminf(wmn, __shfl_xor(wmn, off, 64));
        rmn = fminf(rmn, __shfl_xor(rmn, off, 64));
        rmx = fmaxf(rmx, __shfl_xor(rmx, off, 64));
    }
    if (lane == 0) { red3[0][wid] = wmn; red3[1][wid] = rmn; red3[2][wid] = rmx; }
    __syncthreads();                                           // (1)

    {
        float om = -1e30f;
        for (int j = 0; j < wid; ++j) om = fmaxf(om, wtotmax[j]);
        pm[tid] = fmaxf(pmv, om);
    }
    float wmin = red3[0][0], rmin = red3[1][0], rmax = red3[2][0], wmax = wtotmax[0];
    #pragma unroll
    for (int j = 1; j < 8; ++j) {
        wmin = fminf(wmin, red3[0][j]);
        rmin = fminf(rmin, red3[1][j]);
        rmax = fmaxf(rmax, red3[2][j]);
        wmax = fmaxf(wmax, wtotmax[j]);
    }

    // ---- histograms ----
    const float wscale = 255.0f / fmaxf(wmax - wmin, 1e-30f);
    int wk = (int)((wv - wmin) * wscale);
    wk = wk < 0 ? 0 : (wk > 255 ? 255 : wk);
    atomicAdd(&cnt[wk], 1);
    const float rscale = 255.0f / fmaxf(rmax - rmin, 1e-30f);
    int rk;
    { int kv = (int)((rv - rmin) * rscale); kv = kv < 0 ? 0 : (kv > 255 ? 255 : kv); rk = 255 - kv; }
    atomicAdd(&rcnt[rk], 1);
    atomicMax(&rbmax[rk], __float_as_int(rv));                 // rv > 0
    __syncthreads();                                           // (2)

    // ---- both 256-prefix-sums concurrently: waves 0-3 cnt, waves 4-7 rcnt ----
    int myc = (tid < 256) ? cnt[tid] : rcnt[tid - 256];
    int incl = myc;
    #pragma unroll
    for (int off = 1; off < 64; off <<= 1) {
        int o = __shfl_up(incl, off, 64);
        if (lane >= off) incl += o;
    }
    if (lane == 63) { if (wid < 4) ctot[wid] = incl; else rtot[wid - 4] = incl; }
    __syncthreads();                                           // (3)
    if (tid < 256) {
        int eo = 0;
        for (int j = 0; j < wid; ++j) eo += ctot[j];
        cbase[tid] = eo + incl - myc;
    } else {
        int eo = 0, w2 = wid - 4;
        for (int j = 0; j < w2; ++j) eo += rtot[j];
        rbase[tid - 256] = eo + incl - myc;
    }
    __syncthreads();                                           // (4)

    // ---- scatter (bucket-ordered) ----
    { int p1 = cbase[wk] + atomicAdd(&cslot[wk], 1); wsrt[p1] = wv; }
    { int p2 = rbase[rk] + atomicAdd(&rslot[rk], 1);
      srx_r[p2] = rv; srx_n[p2] = tid; srx_u[p2] = __int_as_float(rbmax[rk]); }
    __syncthreads();                                           // (5)

    // ---- per-bucket f64 sums + 256-prefix (waves 0-3) ----
    double bincl = 0.0, mysum = 0.0;
    if (tid < 256) {
        int st = cbase[tid], e = st + cnt[tid];
        for (int i = st; i < e; ++i) mysum += (double)wsrt[i];
        bincl = mysum;
        #pragma unroll
        for (int off = 1; off < 64; off <<= 1) {
            double o = __shfl_up(bincl, off, 64);
            if (lane >= off) bincl += o;
        }
        if (lane == 63) btot[wid] = bincl;
    }
    __syncthreads();                                           // (6)
    if (tid < 256) {
        double eo = 0.0;
        for (int j = 0; j < wid; ++j) eo += btot[j];
        bsumI[tid] = eo + bincl;
    }
    __syncthreads();                                           // (7)

    if (tid < 256) {
        // ==== phase C: ind_w scan, descending-rel buckets (waves 0-3) ====
        const int b = tid;
        float bv = -1.0f; int bi = 0;
        for (int i = 0; i < 512; ++i) {
            float u = srx_u[i];                      // non-increasing bound
            if (__ballot(u >= bv) == 0ULL) break;
            float r = srx_r[i];
            int   n = srx_n[i];
            float xv = xT[n * B + b];                // coalesced
            float v = fminf(xv, r);
            if (v > bv || (v == bv && n < bi)) { bv = v; bi = n; }
        }
        out[BM + b * M + m] = fminf(x[b * N + bi], worig[bi]);   // chosen_w
    } else {
        // ==== phase D: rel_w CDF + ind_x (waves 4-7) ====
        const int b = tid - 256;
        const float tbm = tT[m * B + b];
        float btf = (tbm - wmin) * wscale;
        int kk; double S;
        if (btf < 0.0f) { kk = 0; S = 0.0; }
        else {
            int bt = (int)btf; bt = bt > 255 ? 255 : bt;
            kk = cbase[bt];
            S = (bt > 0) ? bsumI[bt - 1] : 0.0;
            int e = cbase[bt] + cnt[bt];
            for (int i = cbase[bt]; i < e; ++i) {
                float v = wsrt[i];
                if (v < tbm) { ++kk; S += (double)v; }
            }
        }
        double rw = S + (double)tbm * (double)(512 - kk);
        float c = (float)rw / sum_w[m];
        float tgt = fminf(c, pm[511]);
        int lo = 0, hi = 511;
        while (lo < hi) { int mid = (lo + hi) >> 1; if (pm[mid] >= tgt) hi = mid; else lo = mid + 1; }
        const int ind = lo;
        out[b * M + m] = fminf(x[b * N + ind], worig[ind]);      // chosen_x
    }
}

extern "C" void kernel_launch(void* const* d_in, const int* in_sizes, int n_in,
                              void* d_out, int out_size, void* d_ws, size_t ws_size,
                              hipStream_t stream) {
    const float* x = (const float*)d_in[0];  // (B, N)
    const float* w = (const float*)d_in[1];  // (N, M)
    const float* t = (const float*)d_in[2];  // (B, M)
    float* out = (float*)d_out;

    float* ws = (float*)d_ws;
    float* xT    = ws;                 // 131072
    float* wT    = ws + 131072;        // 262144
    float* tT    = ws + 393216;        // 131072
    float* sum_x = ws + 524288;        // 512
    float* sum_w = ws + 524800;        // 512
    float* px    = ws + 525312;        // 4*NM = 1048576  (~6.3 MB total)

    k_a  <<<644, 256, 0, stream>>>(x, w, t, xT, wT, tT, sum_x, sum_w, px);
    k_col<<<512, 512, 0, stream>>>(x, xT, wT, tT, px, sum_x, sum_w, out);
}